// Round 1
// baseline (1814.285 us; speedup 1.0000x reference)
//
#include <hip/hip_runtime.h>
#include <math.h>

// Problem constants (fixed by the reference)
#define N_NODES 8192
#define N_EDGES 65536
#define F_IN    512
#define HID1    4096
#define HID2    1024
#define F_OUT   10

// ---------------------------------------------------------------------------
// Graph preprocessing: degree -> dis = rsqrt(deg) -> CSR by dst
// ---------------------------------------------------------------------------

__global__ void init_kernel(int* __restrict__ deg, int* __restrict__ cnt) {
    int v = blockIdx.x * blockDim.x + threadIdx.x;
    if (v < N_NODES) { deg[v] = 1; cnt[v] = 0; }  // deg starts at 1 (self loop)
}

__global__ void deg_kernel(const int* __restrict__ ei, int* __restrict__ deg) {
    int e = blockIdx.x * blockDim.x + threadIdx.x;
    if (e < N_EDGES) {
        int d = ei[N_EDGES + e];
        atomicAdd(&deg[d], 1);
    }
}

__global__ void dis_kernel(const int* __restrict__ deg, float* __restrict__ dis) {
    int v = blockIdx.x * blockDim.x + threadIdx.x;
    if (v < N_NODES) dis[v] = rsqrtf((float)deg[v]);
}

// Exclusive scan of in-edge counts (deg-1) over 8192 nodes, one block.
__global__ __launch_bounds__(1024) void scan_kernel(const int* __restrict__ deg,
                                                    int* __restrict__ row_ptr) {
    __shared__ int sums[1024];
    int t = threadIdx.x;
    int base = t * 8;
    int local[8];
    int run = 0;
#pragma unroll
    for (int i = 0; i < 8; i++) { local[i] = run; run += deg[base + i] - 1; }
    sums[t] = run;
    __syncthreads();
    for (int off = 1; off < 1024; off <<= 1) {
        int val = (t >= off) ? sums[t - off] : 0;
        __syncthreads();
        sums[t] += val;
        __syncthreads();
    }
    int offset = (t == 0) ? 0 : sums[t - 1];
#pragma unroll
    for (int i = 0; i < 8; i++) row_ptr[base + i] = offset + local[i];
    if (t == 1023) row_ptr[N_NODES] = sums[1023];
}

__global__ void fill_kernel(const int* __restrict__ ei, const float* __restrict__ dis,
                            const int* __restrict__ row_ptr, int* __restrict__ cnt,
                            int* __restrict__ csr_src, float* __restrict__ csr_w) {
    int e = blockIdx.x * blockDim.x + threadIdx.x;
    if (e < N_EDGES) {
        int s = ei[e];
        int d = ei[N_EDGES + e];
        int slot = row_ptr[d] + atomicAdd(&cnt[d], 1);
        csr_src[slot] = s;
        csr_w[slot] = dis[s] * dis[d];
    }
}

// ---------------------------------------------------------------------------
// Aggregation: out[v,:] = sum_{e: dst=v} w_e * h[src_e,:] + dis[v]^2 * h[v,:]
//              (+bias, relu as template flags). One block (256 thr) per node.
// ---------------------------------------------------------------------------
template <int F, int FPT, bool BIAS, bool RELU>
__global__ __launch_bounds__(256) void agg_kernel(
        const float* __restrict__ h, const int* __restrict__ row_ptr,
        const int* __restrict__ csr_src, const float* __restrict__ csr_w,
        const float* __restrict__ dis, const float* __restrict__ bias,
        float* __restrict__ out) {
    int v = blockIdx.x;
    int tid = threadIdx.x;
    float sw = dis[v];
    sw *= sw;
    float acc[FPT];
#pragma unroll
    for (int i = 0; i < FPT; i++) acc[i] = sw * h[(size_t)v * F + tid + i * 256];
    int beg = row_ptr[v], end = row_ptr[v + 1];
    for (int e = beg; e < end; e++) {
        int s = csr_src[e];
        float w = csr_w[e];
#pragma unroll
        for (int i = 0; i < FPT; i++) acc[i] += w * h[(size_t)s * F + tid + i * 256];
    }
#pragma unroll
    for (int i = 0; i < FPT; i++) {
        float o = acc[i];
        if (BIAS) o += bias[tid + i * 256];
        if (RELU) o = fmaxf(o, 0.0f);
        out[(size_t)v * F + tid + i * 256] = o;
    }
}

// ---------------------------------------------------------------------------
// FP32 tiled GEMM: C[M,N] = A[M,K] @ B[K,N] (+bias, relu). 64x64x16 tiles,
// 256 threads, 4x4 accum/thread. All dims divide the tile sizes (fixed shapes).
// ---------------------------------------------------------------------------
template <bool BIAS, bool RELU>
__global__ __launch_bounds__(256) void gemm_kernel(
        const float* __restrict__ A, const float* __restrict__ B,
        const float* __restrict__ bias, float* __restrict__ C,
        int M, int N, int K) {
    __shared__ float As[16][64];
    __shared__ float Bs[16][64];
    int tid = threadIdx.x;
    int n0 = blockIdx.x * 64;
    int m0 = blockIdx.y * 64;
    int tr = tid >> 4;       // 0..15 -> output rows tr*4..tr*4+3
    int tc = tid & 15;       // 0..15 -> output cols tc*4..tc*4+3
    float acc[4][4] = {};
    for (int k0 = 0; k0 < K; k0 += 16) {
#pragma unroll
        for (int i = 0; i < 4; i++) {
            int idx = tid + i * 256;
            int m = idx >> 4, k = idx & 15;
            As[k][m] = A[(size_t)(m0 + m) * K + k0 + k];
        }
#pragma unroll
        for (int i = 0; i < 4; i++) {
            int idx = tid + i * 256;
            int k = idx >> 6, n = idx & 63;
            Bs[k][n] = B[(size_t)(k0 + k) * N + n0 + n];
        }
        __syncthreads();
#pragma unroll
        for (int k = 0; k < 16; k++) {
            float4 av = *(const float4*)&As[k][tr * 4];
            float4 bv = *(const float4*)&Bs[k][tc * 4];
            float a[4] = {av.x, av.y, av.z, av.w};
            float b[4] = {bv.x, bv.y, bv.z, bv.w};
#pragma unroll
            for (int i = 0; i < 4; i++)
#pragma unroll
                for (int j = 0; j < 4; j++) acc[i][j] += a[i] * b[j];
        }
        __syncthreads();
    }
#pragma unroll
    for (int i = 0; i < 4; i++) {
        int m = m0 + tr * 4 + i;
#pragma unroll
        for (int j = 0; j < 4; j++) {
            int n = n0 + tc * 4 + j;
            float v = acc[i][j];
            if (BIAS) v += bias[n];
            if (RELU) v = fmaxf(v, 0.0f);
            C[(size_t)m * N + n] = v;
        }
    }
}

// ---------------------------------------------------------------------------
// Small GEMM3: H3[8192,10] = A[8192,1024] @ W[1024,10]. One block per row.
// ---------------------------------------------------------------------------
__global__ __launch_bounds__(256) void gemm3_kernel(const float* __restrict__ A,
                                                    const float* __restrict__ W,
                                                    float* __restrict__ H3) {
    int r = blockIdx.x;
    int tid = threadIdx.x;
    float acc[F_OUT] = {};
    for (int k = tid; k < HID2; k += 256) {
        float a = A[(size_t)r * HID2 + k];
#pragma unroll
        for (int c = 0; c < F_OUT; c++) acc[c] += a * W[k * F_OUT + c];
    }
#pragma unroll
    for (int c = 0; c < F_OUT; c++) {
#pragma unroll
        for (int off = 32; off > 0; off >>= 1) acc[c] += __shfl_down(acc[c], off, 64);
    }
    __shared__ float red[4][F_OUT];
    int wave = tid >> 6, lane = tid & 63;
    if (lane == 0) {
#pragma unroll
        for (int c = 0; c < F_OUT; c++) red[wave][c] = acc[c];
    }
    __syncthreads();
    if (tid < F_OUT) {
        float s = red[0][tid] + red[1][tid] + red[2][tid] + red[3][tid];
        H3[r * F_OUT + tid] = s;
    }
}

// ---------------------------------------------------------------------------
// Final: aggregate h3 (F=10), add b3, log_softmax per node. 1 thread / node.
// ---------------------------------------------------------------------------
__global__ void final_kernel(const float* __restrict__ h3, const int* __restrict__ row_ptr,
                             const int* __restrict__ csr_src, const float* __restrict__ csr_w,
                             const float* __restrict__ dis, const float* __restrict__ b3,
                             float* __restrict__ out) {
    int v = blockIdx.x * blockDim.x + threadIdx.x;
    if (v >= N_NODES) return;
    float sw = dis[v] * dis[v];
    float acc[F_OUT];
#pragma unroll
    for (int c = 0; c < F_OUT; c++) acc[c] = b3[c] + sw * h3[v * F_OUT + c];
    int end = row_ptr[v + 1];
    for (int e = row_ptr[v]; e < end; e++) {
        int s = csr_src[e];
        float w = csr_w[e];
#pragma unroll
        for (int c = 0; c < F_OUT; c++) acc[c] += w * h3[s * F_OUT + c];
    }
    float m = acc[0];
#pragma unroll
    for (int c = 1; c < F_OUT; c++) m = fmaxf(m, acc[c]);
    float ssum = 0.0f;
#pragma unroll
    for (int c = 0; c < F_OUT; c++) ssum += expf(acc[c] - m);
    float l = logf(ssum);
#pragma unroll
    for (int c = 0; c < F_OUT; c++) out[v * F_OUT + c] = acc[c] - m - l;
}

// ---------------------------------------------------------------------------
// Launch
// ---------------------------------------------------------------------------
extern "C" void kernel_launch(void* const* d_in, const int* in_sizes, int n_in,
                              void* d_out, int out_size, void* d_ws, size_t ws_size,
                              hipStream_t stream) {
    const float* x  = (const float*)d_in[0];   // [8192, 512]
    const float* W1 = (const float*)d_in[1];   // [512, 4096]
    const float* b1 = (const float*)d_in[2];   // [4096]
    const float* W2 = (const float*)d_in[3];   // [4096, 1024]
    const float* b2 = (const float*)d_in[4];   // [1024]
    const float* W3 = (const float*)d_in[5];   // [1024, 10]
    const float* b3 = (const float*)d_in[6];   // [10]
    const int*   ei = (const int*)d_in[7];     // [2, 65536] int32
    float* out = (float*)d_out;                // [8192, 10]

    // Workspace layout (all offsets 256B-aligned)
    char* p = (char*)d_ws;
    int*   deg     = (int*)p;    p += N_NODES * 4;            // 32 KB
    int*   cnt     = (int*)p;    p += N_NODES * 4;            // 32 KB
    float* dis     = (float*)p;  p += N_NODES * 4;            // 32 KB
    int*   row_ptr = (int*)p;    p += 33024;                  // 8193 ints, padded
    int*   csr_src = (int*)p;    p += N_EDGES * 4;            // 256 KB
    float* csr_w   = (float*)p;  p += N_EDGES * 4;            // 256 KB
    float* h3      = (float*)p;  p += N_NODES * F_OUT * 4;    // 320 KB
    float* agg_x   = (float*)p;  p += (size_t)N_NODES * F_IN * 4;   // 16 MB
    float* h2pre   = (float*)p;  p += (size_t)N_NODES * HID2 * 4;   // 32 MB
    float* agg2    = (float*)p;  p += (size_t)N_NODES * HID2 * 4;   // 32 MB
    float* h1      = (float*)p;  p += (size_t)N_NODES * HID1 * 4;   // 128 MB

    // Graph preprocessing
    init_kernel<<<N_NODES / 256, 256, 0, stream>>>(deg, cnt);
    deg_kernel<<<N_EDGES / 256, 256, 0, stream>>>(ei, deg);
    dis_kernel<<<N_NODES / 256, 256, 0, stream>>>(deg, dis);
    scan_kernel<<<1, 1024, 0, stream>>>(deg, row_ptr);
    fill_kernel<<<N_EDGES / 256, 256, 0, stream>>>(ei, dis, row_ptr, cnt, csr_src, csr_w);

    // Layer 1: agg_x = A @ x ; h1 = relu(agg_x @ W1 + b1)
    agg_kernel<F_IN, F_IN / 256, false, false><<<N_NODES, 256, 0, stream>>>(
        x, row_ptr, csr_src, csr_w, dis, nullptr, agg_x);
    gemm_kernel<true, true><<<dim3(HID1 / 64, N_NODES / 64), 256, 0, stream>>>(
        agg_x, W1, b1, h1, N_NODES, HID1, F_IN);

    // Layer 2: h2pre = h1 @ W2 ; agg2 = relu(A @ h2pre + b2)
    gemm_kernel<false, false><<<dim3(HID2 / 64, N_NODES / 64), 256, 0, stream>>>(
        h1, W2, nullptr, h2pre, N_NODES, HID2, HID1);
    agg_kernel<HID2, HID2 / 256, true, true><<<N_NODES, 256, 0, stream>>>(
        h2pre, row_ptr, csr_src, csr_w, dis, b2, agg2);

    // Layer 3: h3 = agg2 @ W3 ; out = log_softmax(A @ h3 + b3)
    gemm3_kernel<<<N_NODES, 256, 0, stream>>>(agg2, W3, h3);
    final_kernel<<<N_NODES / 256, 256, 0, stream>>>(h3, row_ptr, csr_src, csr_w, dis, b3, out);
}

// Round 2
// 370.542 us; speedup vs baseline: 4.8963x; 4.8963x over previous
//
#include <hip/hip_runtime.h>
#include <math.h>

#define N_NODES 8192
#define N_EDGES 65536
#define F_IN    512
#define HID1    4096
#define HID2    1024
#define F_OUT   10

typedef __bf16 bf16x8 __attribute__((ext_vector_type(8)));
typedef float floatx4 __attribute__((ext_vector_type(4)));

static __device__ __forceinline__ unsigned short f2bf(float f) {
    union { float f; unsigned u; } v; v.f = f;
    unsigned r = v.u + 0x7fffu + ((v.u >> 16) & 1u);   // RNE
    return (unsigned short)(r >> 16);
}

// ---------------------------------------------------------------------------
// Graph preprocessing: degree -> dis = rsqrt(deg) -> CSR by dst
// ---------------------------------------------------------------------------

__global__ void init_kernel(int* __restrict__ deg, int* __restrict__ cnt) {
    int v = blockIdx.x * blockDim.x + threadIdx.x;
    if (v < N_NODES) { deg[v] = 1; cnt[v] = 0; }  // self loop
}

__global__ void deg_kernel(const int* __restrict__ ei, int* __restrict__ deg) {
    int e = blockIdx.x * blockDim.x + threadIdx.x;
    if (e < N_EDGES) atomicAdd(&deg[ei[N_EDGES + e]], 1);
}

__global__ void dis_kernel(const int* __restrict__ deg, float* __restrict__ dis) {
    int v = blockIdx.x * blockDim.x + threadIdx.x;
    if (v < N_NODES) dis[v] = rsqrtf((float)deg[v]);
}

__global__ __launch_bounds__(1024) void scan_kernel(const int* __restrict__ deg,
                                                    int* __restrict__ row_ptr) {
    __shared__ int sums[1024];
    int t = threadIdx.x;
    int base = t * 8;
    int local[8];
    int run = 0;
#pragma unroll
    for (int i = 0; i < 8; i++) { local[i] = run; run += deg[base + i] - 1; }
    sums[t] = run;
    __syncthreads();
    for (int off = 1; off < 1024; off <<= 1) {
        int val = (t >= off) ? sums[t - off] : 0;
        __syncthreads();
        sums[t] += val;
        __syncthreads();
    }
    int offset = (t == 0) ? 0 : sums[t - 1];
#pragma unroll
    for (int i = 0; i < 8; i++) row_ptr[base + i] = offset + local[i];
    if (t == 1023) row_ptr[N_NODES] = sums[1023];
}

__global__ void fill_kernel(const int* __restrict__ ei, const float* __restrict__ dis,
                            const int* __restrict__ row_ptr, int* __restrict__ cnt,
                            int* __restrict__ csr_src, float* __restrict__ csr_w) {
    int e = blockIdx.x * blockDim.x + threadIdx.x;
    if (e < N_EDGES) {
        int s = ei[e];
        int d = ei[N_EDGES + e];
        int slot = row_ptr[d] + atomicAdd(&cnt[d], 1);
        csr_src[slot] = s;
        csr_w[slot] = dis[s] * dis[d];
    }
}

// ---------------------------------------------------------------------------
// Fused transpose + fp32->bf16 convert: W [K,N] f32 -> Wt [N,K] bf16
// ---------------------------------------------------------------------------
__global__ __launch_bounds__(256) void transpose_cvt_kernel(
        const float* __restrict__ W, unsigned short* __restrict__ Wt, int K, int N) {
    __shared__ float t[32][33];
    int tid = threadIdx.x;
    int n0 = blockIdx.x * 32, k0 = blockIdx.y * 32;
    int c = tid & 31, r8 = tid >> 5;
#pragma unroll
    for (int i = 0; i < 4; i++) {
        int r = r8 + i * 8;
        t[r][c] = W[(size_t)(k0 + r) * N + n0 + c];
    }
    __syncthreads();
#pragma unroll
    for (int i = 0; i < 4; i++) {
        int r = r8 + i * 8;   // n index within tile
        Wt[(size_t)(n0 + r) * K + k0 + c] = f2bf(t[c][r]);
    }
}

// ---------------------------------------------------------------------------
// agg1: agg_x[v,:] = sum_e w_e * x[src,:] + dis[v]^2 * x[v,:]  -> bf16 out
// F=512 -> 128 float4/row; 2 nodes per 256-thread block.
// ---------------------------------------------------------------------------
__global__ __launch_bounds__(256) void agg1_kernel(
        const float* __restrict__ x, const int* __restrict__ row_ptr,
        const int* __restrict__ csr_src, const float* __restrict__ csr_w,
        const float* __restrict__ dis, unsigned short* __restrict__ out) {
    int v = blockIdx.x * 2 + (threadIdx.x >> 7);
    int t = threadIdx.x & 127;
    const float4* x4 = (const float4*)x;       // row stride 128
    float sw = dis[v]; sw *= sw;
    float4 a = x4[(size_t)v * 128 + t];
    float ax = sw * a.x, ay = sw * a.y, az = sw * a.z, aw = sw * a.w;
    int end = row_ptr[v + 1];
    for (int e = row_ptr[v]; e < end; e++) {
        int s = csr_src[e];
        float w = csr_w[e];
        float4 b = x4[(size_t)s * 128 + t];
        ax += w * b.x; ay += w * b.y; az += w * b.z; aw += w * b.w;
    }
    ushort4 o;
    o.x = f2bf(ax); o.y = f2bf(ay); o.z = f2bf(az); o.w = f2bf(aw);
    ((ushort4*)out)[(size_t)v * 128 + t] = o;
}

// ---------------------------------------------------------------------------
// agg2: agg2[v,:] = relu(sum_e w_e * h[src,:] + dis[v]^2*h[v,:] + b2) -> f32
// F=1024 -> 256 float4/row; 1 node per block.
// ---------------------------------------------------------------------------
__global__ __launch_bounds__(256) void agg2_kernel(
        const float* __restrict__ h, const int* __restrict__ row_ptr,
        const int* __restrict__ csr_src, const float* __restrict__ csr_w,
        const float* __restrict__ dis, const float* __restrict__ bias,
        float* __restrict__ out) {
    int v = blockIdx.x;
    int t = threadIdx.x;
    const float4* h4 = (const float4*)h;       // row stride 256
    float sw = dis[v]; sw *= sw;
    float4 a = h4[(size_t)v * 256 + t];
    float ax = sw * a.x, ay = sw * a.y, az = sw * a.z, aw = sw * a.w;
    int end = row_ptr[v + 1];
    for (int e = row_ptr[v]; e < end; e++) {
        int s = csr_src[e];
        float w = csr_w[e];
        float4 b = h4[(size_t)s * 256 + t];
        ax += w * b.x; ay += w * b.y; az += w * b.z; aw += w * b.w;
    }
    float4 bb = ((const float4*)bias)[t];
    float4 o;
    o.x = fmaxf(ax + bb.x, 0.0f); o.y = fmaxf(ay + bb.y, 0.0f);
    o.z = fmaxf(az + bb.z, 0.0f); o.w = fmaxf(aw + bb.w, 0.0f);
    ((float4*)out)[(size_t)v * 256 + t] = o;
}

// ---------------------------------------------------------------------------
// MFMA bf16 GEMM (m97 structure): C[M,N] = A[M,K] @ Bt[N,K]^T (+bias,relu)
// 128x128 tile, BK=32, 256 threads = 4 waves (2x2), 64x64 per wave,
// global_load_lds width-16 staging, 2-barrier K-loop.
// ---------------------------------------------------------------------------
template <bool OUT_BF16, bool BIAS, bool RELU>
__global__ __launch_bounds__(256) void gemm_mfma_kernel(
        const unsigned short* __restrict__ A,   // [M,K] bf16
        const unsigned short* __restrict__ Bt,  // [N,K] bf16
        const float* __restrict__ bias,         // [N] or null
        void* __restrict__ C,                   // [M,N] bf16 or f32
        int M, int N, int K) {
    __shared__ unsigned short As[128 * 32];
    __shared__ unsigned short Bs[128 * 32];
    int tid = threadIdx.x;
    int wave = tid >> 6, lane = tid & 63;
    int wm = wave >> 1, wn = wave & 1;
    int m0 = blockIdx.y * 128, n0 = blockIdx.x * 128;
    int lrow = lane & 15, lquad = lane >> 4;

    floatx4 acc[4][4] = {};

    for (int k0 = 0; k0 < K; k0 += 32) {
#pragma unroll
        for (int j = 0; j < 2; j++) {
            int idx = j * 256 + tid;
            int r = idx >> 2;
            int kk = (idx & 3) * 8;
            __builtin_amdgcn_global_load_lds(
                (const __attribute__((address_space(1))) void*)(A + (size_t)(m0 + r) * K + k0 + kk),
                (__attribute__((address_space(3))) void*)(&As[idx * 8]), 16, 0, 0);
            __builtin_amdgcn_global_load_lds(
                (const __attribute__((address_space(1))) void*)(Bt + (size_t)(n0 + r) * K + k0 + kk),
                (__attribute__((address_space(3))) void*)(&Bs[idx * 8]), 16, 0, 0);
        }
        __syncthreads();
        bf16x8 af[4], bfr[4];
#pragma unroll
        for (int mt = 0; mt < 4; mt++)
            af[mt] = *(const bf16x8*)&As[(wm * 64 + mt * 16 + lrow) * 32 + lquad * 8];
#pragma unroll
        for (int nt = 0; nt < 4; nt++)
            bfr[nt] = *(const bf16x8*)&Bs[(wn * 64 + nt * 16 + lrow) * 32 + lquad * 8];
#pragma unroll
        for (int mt = 0; mt < 4; mt++)
#pragma unroll
            for (int nt = 0; nt < 4; nt++)
                acc[mt][nt] = __builtin_amdgcn_mfma_f32_16x16x32_bf16(
                    af[mt], bfr[nt], acc[mt][nt], 0, 0, 0);
        __syncthreads();
    }

#pragma unroll
    for (int mt = 0; mt < 4; mt++) {
#pragma unroll
        for (int nt = 0; nt < 4; nt++) {
            int col = n0 + wn * 64 + nt * 16 + lrow;
            float bv = BIAS ? bias[col] : 0.0f;
#pragma unroll
            for (int r = 0; r < 4; r++) {
                int row = m0 + wm * 64 + mt * 16 + lquad * 4 + r;
                float v = acc[mt][nt][r] + bv;
                if (RELU) v = fmaxf(v, 0.0f);
                if (OUT_BF16)
                    ((unsigned short*)C)[(size_t)row * N + col] = f2bf(v);
                else
                    ((float*)C)[(size_t)row * N + col] = v;
            }
        }
    }
}

// ---------------------------------------------------------------------------
// GEMM3: H3[8192,10] = A[8192,1024] @ W[1024,10]. One block per row.
// ---------------------------------------------------------------------------
__global__ __launch_bounds__(256) void gemm3_kernel(const float* __restrict__ A,
                                                    const float* __restrict__ W,
                                                    float* __restrict__ H3) {
    int r = blockIdx.x;
    int tid = threadIdx.x;
    float acc[F_OUT] = {};
    float4 a = ((const float4*)A)[(size_t)r * 256 + tid];
    int k = tid * 4;
#pragma unroll
    for (int c = 0; c < F_OUT; c++)
        acc[c] = a.x * W[k * F_OUT + c] + a.y * W[(k + 1) * F_OUT + c] +
                 a.z * W[(k + 2) * F_OUT + c] + a.w * W[(k + 3) * F_OUT + c];
#pragma unroll
    for (int c = 0; c < F_OUT; c++) {
#pragma unroll
        for (int off = 32; off > 0; off >>= 1) acc[c] += __shfl_down(acc[c], off, 64);
    }
    __shared__ float red[4][F_OUT];
    int wave = tid >> 6, lane = tid & 63;
    if (lane == 0) {
#pragma unroll
        for (int c = 0; c < F_OUT; c++) red[wave][c] = acc[c];
    }
    __syncthreads();
    if (tid < F_OUT) {
        float s = red[0][tid] + red[1][tid] + red[2][tid] + red[3][tid];
        H3[r * F_OUT + tid] = s;
    }
}

// ---------------------------------------------------------------------------
// Final: aggregate h3 (F=10), add b3, log_softmax per node.
// ---------------------------------------------------------------------------
__global__ void final_kernel(const float* __restrict__ h3, const int* __restrict__ row_ptr,
                             const int* __restrict__ csr_src, const float* __restrict__ csr_w,
                             const float* __restrict__ dis, const float* __restrict__ b3,
                             float* __restrict__ out) {
    int v = blockIdx.x * blockDim.x + threadIdx.x;
    if (v >= N_NODES) return;
    float sw = dis[v] * dis[v];
    float acc[F_OUT];
#pragma unroll
    for (int c = 0; c < F_OUT; c++) acc[c] = b3[c] + sw * h3[v * F_OUT + c];
    int end = row_ptr[v + 1];
    for (int e = row_ptr[v]; e < end; e++) {
        int s = csr_src[e];
        float w = csr_w[e];
#pragma unroll
        for (int c = 0; c < F_OUT; c++) acc[c] += w * h3[s * F_OUT + c];
    }
    float m = acc[0];
#pragma unroll
    for (int c = 1; c < F_OUT; c++) m = fmaxf(m, acc[c]);
    float ssum = 0.0f;
#pragma unroll
    for (int c = 0; c < F_OUT; c++) ssum += expf(acc[c] - m);
    float l = logf(ssum);
#pragma unroll
    for (int c = 0; c < F_OUT; c++) out[v * F_OUT + c] = acc[c] - m - l;
}

// ---------------------------------------------------------------------------
// Launch
// ---------------------------------------------------------------------------
extern "C" void kernel_launch(void* const* d_in, const int* in_sizes, int n_in,
                              void* d_out, int out_size, void* d_ws, size_t ws_size,
                              hipStream_t stream) {
    const float* x  = (const float*)d_in[0];   // [8192, 512]
    const float* W1 = (const float*)d_in[1];   // [512, 4096]
    const float* b1 = (const float*)d_in[2];   // [4096]
    const float* W2 = (const float*)d_in[3];   // [4096, 1024]
    const float* b2 = (const float*)d_in[4];   // [1024]
    const float* W3 = (const float*)d_in[5];   // [1024, 10]
    const float* b3 = (const float*)d_in[6];   // [10]
    const int*   ei = (const int*)d_in[7];     // [2, 65536]
    float* out = (float*)d_out;                // [8192, 10]

    // Workspace layout (256B-aligned sections)
    char* p = (char*)d_ws;
    int*   deg     = (int*)p;    p += N_NODES * 4;
    int*   cnt     = (int*)p;    p += N_NODES * 4;
    float* dis     = (float*)p;  p += N_NODES * 4;
    int*   row_ptr = (int*)p;    p += 33024;
    int*   csr_src = (int*)p;    p += N_EDGES * 4;
    float* csr_w   = (float*)p;  p += N_EDGES * 4;
    float* h3      = (float*)p;  p += N_NODES * F_OUT * 4;
    unsigned short* agg_x = (unsigned short*)p; p += (size_t)N_NODES * F_IN * 2;   // 8 MB
    unsigned short* W1t   = (unsigned short*)p; p += (size_t)HID1 * F_IN * 2;      // 4 MB
    unsigned short* W2t   = (unsigned short*)p; p += (size_t)HID2 * HID1 * 2;      // 8 MB
    unsigned short* h1    = (unsigned short*)p; p += (size_t)N_NODES * HID1 * 2;   // 64 MB
    float* h2pre  = (float*)p;  p += (size_t)N_NODES * HID2 * 4;                   // 32 MB
    float* agg2   = (float*)p;  p += (size_t)N_NODES * HID2 * 4;                   // 32 MB

    // Graph preprocessing
    init_kernel<<<N_NODES / 256, 256, 0, stream>>>(deg, cnt);
    deg_kernel<<<N_EDGES / 256, 256, 0, stream>>>(ei, deg);
    dis_kernel<<<N_NODES / 256, 256, 0, stream>>>(deg, dis);
    scan_kernel<<<1, 1024, 0, stream>>>(deg, row_ptr);
    fill_kernel<<<N_EDGES / 256, 256, 0, stream>>>(ei, dis, row_ptr, cnt, csr_src, csr_w);

    // Weight transpose+cvt (independent of graph path)
    transpose_cvt_kernel<<<dim3(HID1 / 32, F_IN / 32), 256, 0, stream>>>(W1, W1t, F_IN, HID1);
    transpose_cvt_kernel<<<dim3(HID2 / 32, HID1 / 32), 256, 0, stream>>>(W2, W2t, HID1, HID2);

    // Layer 1: agg_x = A @ x (bf16) ; h1 = relu(agg_x @ W1 + b1) (bf16)
    agg1_kernel<<<N_NODES / 2, 256, 0, stream>>>(x, row_ptr, csr_src, csr_w, dis, agg_x);
    gemm_mfma_kernel<true, true, true><<<dim3(HID1 / 128, N_NODES / 128), 256, 0, stream>>>(
        agg_x, W1t, b1, h1, N_NODES, HID1, F_IN);

    // Layer 2: h2pre = h1 @ W2 (f32) ; agg2 = relu(A @ h2pre + b2)
    gemm_mfma_kernel<false, false, false><<<dim3(HID2 / 128, N_NODES / 128), 256, 0, stream>>>(
        h1, W2t, nullptr, h2pre, N_NODES, HID2, HID1);
    agg2_kernel<<<N_NODES, 256, 0, stream>>>(h2pre, row_ptr, csr_src, csr_w, dis, b2, agg2);

    // Layer 3: h3 = agg2 @ W3 ; out = log_softmax(A @ h3 + b3)
    gemm3_kernel<<<N_NODES, 256, 0, stream>>>(agg2, W3, h3);
    final_kernel<<<N_NODES / 256, 256, 0, stream>>>(h3, row_ptr, csr_src, csr_w, dis, b3, out);
}

// Round 3
// 318.705 us; speedup vs baseline: 5.6927x; 1.1626x over previous
//
#include <hip/hip_runtime.h>
#include <math.h>

#define N_NODES 8192
#define N_EDGES 65536
#define F_IN    512
#define HID1    4096
#define HID2    1024
#define F_OUT   10

typedef __bf16 bf16x8 __attribute__((ext_vector_type(8)));
typedef float floatx4 __attribute__((ext_vector_type(4)));

static __device__ __forceinline__ unsigned short f2bf(float f) {
    union { float f; unsigned u; } v; v.f = f;
    unsigned r = v.u + 0x7fffu + ((v.u >> 16) & 1u);   // RNE
    return (unsigned short)(r >> 16);
}
static __device__ __forceinline__ float bf2f(unsigned short u) {
    union { unsigned u; float f; } v; v.u = ((unsigned)u) << 16;
    return v.f;
}

// ---------------------------------------------------------------------------
// Graph preprocessing
// ---------------------------------------------------------------------------
__global__ void init_kernel(int* __restrict__ deg, int* __restrict__ cnt) {
    int v = blockIdx.x * blockDim.x + threadIdx.x;
    if (v < N_NODES) { deg[v] = 1; cnt[v] = 0; }  // self loop
}

__global__ void deg_kernel(const int* __restrict__ ei, int* __restrict__ deg) {
    int e = blockIdx.x * blockDim.x + threadIdx.x;
    if (e < N_EDGES) atomicAdd(&deg[ei[N_EDGES + e]], 1);
}

__global__ __launch_bounds__(1024) void scan_kernel(const int* __restrict__ deg,
                                                    int* __restrict__ row_ptr) {
    __shared__ int sums[1024];
    int t = threadIdx.x;
    int base = t * 8;
    int local[8];
    int run = 0;
#pragma unroll
    for (int i = 0; i < 8; i++) { local[i] = run; run += deg[base + i] - 1; }
    sums[t] = run;
    __syncthreads();
    for (int off = 1; off < 1024; off <<= 1) {
        int val = (t >= off) ? sums[t - off] : 0;
        __syncthreads();
        sums[t] += val;
        __syncthreads();
    }
    int offset = (t == 0) ? 0 : sums[t - 1];
#pragma unroll
    for (int i = 0; i < 8; i++) row_ptr[base + i] = offset + local[i];
    if (t == 1023) row_ptr[N_NODES] = sums[1023];
}

__global__ void fill_kernel(const int* __restrict__ ei, const int* __restrict__ deg,
                            const int* __restrict__ row_ptr, int* __restrict__ cnt,
                            int* __restrict__ csr_src, float* __restrict__ csr_w) {
    int e = blockIdx.x * blockDim.x + threadIdx.x;
    if (e < N_EDGES) {
        int s = ei[e];
        int d = ei[N_EDGES + e];
        int slot = row_ptr[d] + atomicAdd(&cnt[d], 1);
        csr_src[slot] = s;
        csr_w[slot] = rsqrtf((float)(deg[s] * deg[d]));
    }
}

// ---------------------------------------------------------------------------
// x (f32) -> bf16
// ---------------------------------------------------------------------------
__global__ __launch_bounds__(256) void xcvt_kernel(const float* __restrict__ x,
                                                   unsigned short* __restrict__ xb) {
    int i = blockIdx.x * blockDim.x + threadIdx.x;   // float4 index
    float4 a = ((const float4*)x)[i];
    ushort4 o;
    o.x = f2bf(a.x); o.y = f2bf(a.y); o.z = f2bf(a.z); o.w = f2bf(a.w);
    ((ushort4*)xb)[i] = o;
}

// ---------------------------------------------------------------------------
// Transpose + cvt: W [K,N] f32 -> Wt [N,K] bf16
// ---------------------------------------------------------------------------
__global__ __launch_bounds__(256) void transpose_cvt_kernel(
        const float* __restrict__ W, unsigned short* __restrict__ Wt, int K, int N) {
    __shared__ float t[32][33];
    int tid = threadIdx.x;
    int n0 = blockIdx.x * 32, k0 = blockIdx.y * 32;
    int c = tid & 31, r8 = tid >> 5;
#pragma unroll
    for (int i = 0; i < 4; i++) {
        int r = r8 + i * 8;
        t[r][c] = W[(size_t)(k0 + r) * N + n0 + c];
    }
    __syncthreads();
#pragma unroll
    for (int i = 0; i < 4; i++) {
        int r = r8 + i * 8;
        Wt[(size_t)(n0 + r) * K + k0 + c] = f2bf(t[c][r]);
    }
}

// ---------------------------------------------------------------------------
// agg1: agg_x[v,:] = sum_e w_e*xb[src,:] + (1/deg)*xb[v,:] -> bf16
// F=512 bf16: 128 lanes/node x ushort4; 2 nodes per block.
// ---------------------------------------------------------------------------
__global__ __launch_bounds__(256) void agg1_kernel(
        const unsigned short* __restrict__ xb, const int* __restrict__ row_ptr,
        const int* __restrict__ csr_src, const float* __restrict__ csr_w,
        const int* __restrict__ deg, unsigned short* __restrict__ out) {
    int v = blockIdx.x * 2 + (threadIdx.x >> 7);
    int t = threadIdx.x & 127;
    const ushort4* x4 = (const ushort4*)xb;    // row stride 128
    float sw = 1.0f / (float)deg[v];
    ushort4 a = x4[(size_t)v * 128 + t];
    float ax = sw * bf2f(a.x), ay = sw * bf2f(a.y), az = sw * bf2f(a.z), aw = sw * bf2f(a.w);
    int end = row_ptr[v + 1];
    for (int e = row_ptr[v]; e < end; e++) {
        int s = csr_src[e];
        float w = csr_w[e];
        ushort4 b = x4[(size_t)s * 128 + t];
        ax += w * bf2f(b.x); ay += w * bf2f(b.y); az += w * bf2f(b.z); aw += w * bf2f(b.w);
    }
    ushort4 o;
    o.x = f2bf(ax); o.y = f2bf(ay); o.z = f2bf(az); o.w = f2bf(aw);
    ((ushort4*)out)[(size_t)v * 128 + t] = o;
}

// ---------------------------------------------------------------------------
// agg2: relu(sum_e w_e*h[src,:] + (1/deg)*h[v,:] + b2) -> bf16
// F=1024 bf16: 256 lanes x ushort4; 1 node per block.
// ---------------------------------------------------------------------------
__global__ __launch_bounds__(256) void agg2_kernel(
        const unsigned short* __restrict__ h, const int* __restrict__ row_ptr,
        const int* __restrict__ csr_src, const float* __restrict__ csr_w,
        const int* __restrict__ deg, const float* __restrict__ bias,
        unsigned short* __restrict__ out) {
    int v = blockIdx.x;
    int t = threadIdx.x;
    const ushort4* h4 = (const ushort4*)h;     // row stride 256
    float sw = 1.0f / (float)deg[v];
    ushort4 a = h4[(size_t)v * 256 + t];
    float ax = sw * bf2f(a.x), ay = sw * bf2f(a.y), az = sw * bf2f(a.z), aw = sw * bf2f(a.w);
    int end = row_ptr[v + 1];
    for (int e = row_ptr[v]; e < end; e++) {
        int s = csr_src[e];
        float w = csr_w[e];
        ushort4 b = h4[(size_t)s * 256 + t];
        ax += w * bf2f(b.x); ay += w * bf2f(b.y); az += w * bf2f(b.z); aw += w * bf2f(b.w);
    }
    float4 bb = ((const float4*)bias)[t];
    ushort4 o;
    o.x = f2bf(fmaxf(ax + bb.x, 0.0f)); o.y = f2bf(fmaxf(ay + bb.y, 0.0f));
    o.z = f2bf(fmaxf(az + bb.z, 0.0f)); o.w = f2bf(fmaxf(aw + bb.w, 0.0f));
    ((ushort4*)out)[(size_t)v * 256 + t] = o;
}

// ---------------------------------------------------------------------------
// MFMA bf16 GEMM: C[M,N] = A[M,K] @ Bt[N,K]^T (+bias,relu)
// 128x128 tile, BK=64, XOR-swizzled LDS (conflict-free b128 reads),
// XCD-aware block swizzle, global_load_lds width-16 staging.
// ---------------------------------------------------------------------------
template <bool OUT_BF16, bool BIAS, bool RELU>
__global__ __launch_bounds__(256) void gemm_mfma_kernel(
        const unsigned short* __restrict__ A,   // [M,K] bf16
        const unsigned short* __restrict__ Bt,  // [N,K] bf16
        const float* __restrict__ bias,         // [N] or null
        void* __restrict__ C,                   // [M,N] bf16 or f32
        int M, int N, int K) {
    __shared__ unsigned short As[128 * 64];
    __shared__ unsigned short Bs[128 * 64];
    int tid = threadIdx.x;
    int wave = tid >> 6, lane = tid & 63;
    int wm = wave >> 1, wn = wave & 1;
    // XCD swizzle: blocks with same m-tile land on the same XCD (b%8 const)
    int GN = N >> 7;
    int b = blockIdx.x;
    int ntile = (b >> 3) % GN;
    int mtile = ((b >> 3) / GN) * 8 + (b & 7);
    int m0 = mtile * 128, n0 = ntile * 128;
    int lrow = lane & 15, lquad = lane >> 4;

    floatx4 acc[4][4] = {};

    for (int k0 = 0; k0 < K; k0 += 64) {
#pragma unroll
        for (int j = 0; j < 4; j++) {
            int idx = j * 256 + tid;            // LDS 16B-slot 0..1023
            int r = idx >> 3;                   // row 0..127
            int kc = (idx & 7) ^ (r & 7);       // source chunk (XOR swizzle)
            __builtin_amdgcn_global_load_lds(
                (const __attribute__((address_space(1))) void*)(A + (size_t)(m0 + r) * K + k0 + kc * 8),
                (__attribute__((address_space(3))) void*)(&As[idx * 8]), 16, 0, 0);
            __builtin_amdgcn_global_load_lds(
                (const __attribute__((address_space(1))) void*)(Bt + (size_t)(n0 + r) * K + k0 + kc * 8),
                (__attribute__((address_space(3))) void*)(&Bs[idx * 8]), 16, 0, 0);
        }
        __syncthreads();
#pragma unroll
        for (int kk = 0; kk < 2; kk++) {
            bf16x8 af[4], bfr[4];
#pragma unroll
            for (int mt = 0; mt < 4; mt++) {
                int R = wm * 64 + mt * 16 + lrow;
                int c = kk * 4 + lquad;
                af[mt] = *(const bf16x8*)&As[(R * 8 + (c ^ (R & 7))) * 8];
            }
#pragma unroll
            for (int nt = 0; nt < 4; nt++) {
                int R = wn * 64 + nt * 16 + lrow;
                int c = kk * 4 + lquad;
                bfr[nt] = *(const bf16x8*)&Bs[(R * 8 + (c ^ (R & 7))) * 8];
            }
#pragma unroll
            for (int mt = 0; mt < 4; mt++)
#pragma unroll
                for (int nt = 0; nt < 4; nt++)
                    acc[mt][nt] = __builtin_amdgcn_mfma_f32_16x16x32_bf16(
                        af[mt], bfr[nt], acc[mt][nt], 0, 0, 0);
        }
        __syncthreads();
    }

#pragma unroll
    for (int mt = 0; mt < 4; mt++) {
#pragma unroll
        for (int nt = 0; nt < 4; nt++) {
            int col = n0 + wn * 64 + nt * 16 + lrow;
            float bv = BIAS ? bias[col] : 0.0f;
#pragma unroll
            for (int r = 0; r < 4; r++) {
                int row = m0 + wm * 64 + mt * 16 + lquad * 4 + r;
                float v = acc[mt][nt][r] + bv;
                if (RELU) v = fmaxf(v, 0.0f);
                if (OUT_BF16)
                    ((unsigned short*)C)[(size_t)row * N + col] = f2bf(v);
                else
                    ((float*)C)[(size_t)row * N + col] = v;
            }
        }
    }
}

// ---------------------------------------------------------------------------
// GEMM3: H3[8192,10] = agg2b[8192,1024](bf16) @ W[1024,10](f32)
// ---------------------------------------------------------------------------
__global__ __launch_bounds__(256) void gemm3_kernel(const unsigned short* __restrict__ A,
                                                    const float* __restrict__ W,
                                                    float* __restrict__ H3) {
    int r = blockIdx.x;
    int tid = threadIdx.x;
    float acc[F_OUT];
    ushort4 a4 = ((const ushort4*)A)[(size_t)r * 256 + tid];
    float a0 = bf2f(a4.x), a1 = bf2f(a4.y), a2 = bf2f(a4.z), a3 = bf2f(a4.w);
    int k = tid * 4;
#pragma unroll
    for (int c = 0; c < F_OUT; c++)
        acc[c] = a0 * W[k * F_OUT + c] + a1 * W[(k + 1) * F_OUT + c] +
                 a2 * W[(k + 2) * F_OUT + c] + a3 * W[(k + 3) * F_OUT + c];
#pragma unroll
    for (int c = 0; c < F_OUT; c++) {
#pragma unroll
        for (int off = 32; off > 0; off >>= 1) acc[c] += __shfl_down(acc[c], off, 64);
    }
    __shared__ float red[4][F_OUT];
    int wave = tid >> 6, lane = tid & 63;
    if (lane == 0) {
#pragma unroll
        for (int c = 0; c < F_OUT; c++) red[wave][c] = acc[c];
    }
    __syncthreads();
    if (tid < F_OUT) {
        float s = red[0][tid] + red[1][tid] + red[2][tid] + red[3][tid];
        H3[r * F_OUT + tid] = s;
    }
}

// ---------------------------------------------------------------------------
// Final: aggregate h3 (F=10), add b3, log_softmax per node.
// ---------------------------------------------------------------------------
__global__ void final_kernel(const float* __restrict__ h3, const int* __restrict__ row_ptr,
                             const int* __restrict__ csr_src, const float* __restrict__ csr_w,
                             const int* __restrict__ deg, const float* __restrict__ b3,
                             float* __restrict__ out) {
    int v = blockIdx.x * blockDim.x + threadIdx.x;
    if (v >= N_NODES) return;
    float sw = 1.0f / (float)deg[v];
    float acc[F_OUT];
#pragma unroll
    for (int c = 0; c < F_OUT; c++) acc[c] = b3[c] + sw * h3[v * F_OUT + c];
    int end = row_ptr[v + 1];
    for (int e = row_ptr[v]; e < end; e++) {
        int s = csr_src[e];
        float w = csr_w[e];
#pragma unroll
        for (int c = 0; c < F_OUT; c++) acc[c] += w * h3[s * F_OUT + c];
    }
    float m = acc[0];
#pragma unroll
    for (int c = 1; c < F_OUT; c++) m = fmaxf(m, acc[c]);
    float ssum = 0.0f;
#pragma unroll
    for (int c = 0; c < F_OUT; c++) ssum += expf(acc[c] - m);
    float l = logf(ssum);
#pragma unroll
    for (int c = 0; c < F_OUT; c++) out[v * F_OUT + c] = acc[c] - m - l;
}

// ---------------------------------------------------------------------------
// Launch
// ---------------------------------------------------------------------------
extern "C" void kernel_launch(void* const* d_in, const int* in_sizes, int n_in,
                              void* d_out, int out_size, void* d_ws, size_t ws_size,
                              hipStream_t stream) {
    const float* x  = (const float*)d_in[0];
    const float* W1 = (const float*)d_in[1];
    const float* b1 = (const float*)d_in[2];
    const float* W2 = (const float*)d_in[3];
    const float* b2 = (const float*)d_in[4];
    const float* W3 = (const float*)d_in[5];
    const float* b3 = (const float*)d_in[6];
    const int*   ei = (const int*)d_in[7];
    float* out = (float*)d_out;

    char* p = (char*)d_ws;
    int*   deg     = (int*)p;    p += N_NODES * 4;
    int*   cnt     = (int*)p;    p += N_NODES * 4;
    int*   row_ptr = (int*)p;    p += 33024;
    int*   csr_src = (int*)p;    p += N_EDGES * 4;
    float* csr_w   = (float*)p;  p += N_EDGES * 4;
    float* h3      = (float*)p;  p += N_NODES * F_OUT * 4;
    unsigned short* xb    = (unsigned short*)p; p += (size_t)N_NODES * F_IN * 2;   // 8 MB
    unsigned short* agg_x = (unsigned short*)p; p += (size_t)N_NODES * F_IN * 2;   // 8 MB
    unsigned short* W1t   = (unsigned short*)p; p += (size_t)HID1 * F_IN * 2;      // 4 MB
    unsigned short* W2t   = (unsigned short*)p; p += (size_t)HID2 * HID1 * 2;      // 8 MB
    unsigned short* h1    = (unsigned short*)p; p += (size_t)N_NODES * HID1 * 2;   // 64 MB
    unsigned short* h2pre = (unsigned short*)p; p += (size_t)N_NODES * HID2 * 2;   // 16 MB
    unsigned short* agg2b = (unsigned short*)p; p += (size_t)N_NODES * HID2 * 2;   // 16 MB

    // Graph preprocessing
    init_kernel<<<N_NODES / 256, 256, 0, stream>>>(deg, cnt);
    deg_kernel<<<N_EDGES / 256, 256, 0, stream>>>(ei, deg);
    scan_kernel<<<1, 1024, 0, stream>>>(deg, row_ptr);
    fill_kernel<<<N_EDGES / 256, 256, 0, stream>>>(ei, deg, row_ptr, cnt, csr_src, csr_w);

    // Conversions (independent of graph path)
    xcvt_kernel<<<(N_NODES * F_IN / 4) / 256, 256, 0, stream>>>(x, xb);
    transpose_cvt_kernel<<<dim3(HID1 / 32, F_IN / 32), 256, 0, stream>>>(W1, W1t, F_IN, HID1);
    transpose_cvt_kernel<<<dim3(HID2 / 32, HID1 / 32), 256, 0, stream>>>(W2, W2t, HID1, HID2);

    // Layer 1
    agg1_kernel<<<N_NODES / 2, 256, 0, stream>>>(xb, row_ptr, csr_src, csr_w, deg, agg_x);
    gemm_mfma_kernel<true, true, true><<<(HID1 / 128) * (N_NODES / 128), 256, 0, stream>>>(
        agg_x, W1t, b1, h1, N_NODES, HID1, F_IN);

    // Layer 2
    gemm_mfma_kernel<true, false, false><<<(HID2 / 128) * (N_NODES / 128), 256, 0, stream>>>(
        h1, W2t, nullptr, h2pre, N_NODES, HID2, HID1);
    agg2_kernel<<<N_NODES, 256, 0, stream>>>(h2pre, row_ptr, csr_src, csr_w, deg, b2, agg2b);

    // Layer 3
    gemm3_kernel<<<N_NODES, 256, 0, stream>>>(agg2b, W3, h3);
    final_kernel<<<N_NODES / 256, 256, 0, stream>>>(h3, row_ptr, csr_src, csr_w, deg, b3, out);
}

// Round 4
// 301.055 us; speedup vs baseline: 6.0264x; 1.0586x over previous
//
#include <hip/hip_runtime.h>
#include <math.h>

#define N_NODES 8192
#define N_EDGES 65536
#define F_IN    512
#define HID1    4096
#define HID2    1024
#define F_OUT   10
#define H3_STRIDE 12

typedef __bf16 bf16x8 __attribute__((ext_vector_type(8)));
typedef float floatx4 __attribute__((ext_vector_type(4)));

static __device__ __forceinline__ unsigned short f2bf(float f) {
    union { float f; unsigned u; } v; v.f = f;
    unsigned r = v.u + 0x7fffu + ((v.u >> 16) & 1u);   // RNE
    return (unsigned short)(r >> 16);
}
static __device__ __forceinline__ float bf2f(unsigned short u) {
    union { unsigned u; float f; } v; v.u = ((unsigned)u) << 16;
    return v.f;
}

// ---------------------------------------------------------------------------
// Graph preprocessing. deg[] = in-edge count (self-loop NOT included; use
// deg+1 wherever total degree is needed).
// ---------------------------------------------------------------------------
__global__ void deg_kernel(const int* __restrict__ ei, int* __restrict__ deg) {
    int e = blockIdx.x * blockDim.x + threadIdx.x;
    if (e < N_EDGES) atomicAdd(&deg[ei[N_EDGES + e]], 1);
}

// Exclusive scan of in-edge counts; also zeroes cnt[].
__global__ __launch_bounds__(1024) void scan_kernel(const int* __restrict__ deg,
                                                    int* __restrict__ row_ptr,
                                                    int* __restrict__ cnt) {
    __shared__ int sums[1024];
    int t = threadIdx.x;
    int base = t * 8;
    int local[8];
    int run = 0;
#pragma unroll
    for (int i = 0; i < 8; i++) { local[i] = run; run += deg[base + i]; cnt[base + i] = 0; }
    sums[t] = run;
    __syncthreads();
    for (int off = 1; off < 1024; off <<= 1) {
        int val = (t >= off) ? sums[t - off] : 0;
        __syncthreads();
        sums[t] += val;
        __syncthreads();
    }
    int offset = (t == 0) ? 0 : sums[t - 1];
#pragma unroll
    for (int i = 0; i < 8; i++) row_ptr[base + i] = offset + local[i];
    if (t == 1023) row_ptr[N_NODES] = sums[1023];
}

__global__ void fill_kernel(const int* __restrict__ ei, const int* __restrict__ deg,
                            const int* __restrict__ row_ptr, int* __restrict__ cnt,
                            int* __restrict__ csr_src, float* __restrict__ csr_w) {
    int e = blockIdx.x * blockDim.x + threadIdx.x;
    if (e < N_EDGES) {
        int s = ei[e];
        int d = ei[N_EDGES + e];
        int slot = row_ptr[d] + atomicAdd(&cnt[d], 1);
        csr_src[slot] = s;
        csr_w[slot] = rsqrtf((float)((deg[s] + 1) * (deg[d] + 1)));
    }
}

// ---------------------------------------------------------------------------
// prep: xcvt (blocks 0..4095) + W1 transpose (4096..6143) + W2 transpose
// (6144..10239), one launch.
// ---------------------------------------------------------------------------
static __device__ __forceinline__ void transpose_body(
        const float* __restrict__ W, unsigned short* __restrict__ Wt,
        int K, int N, int k0, int n0, int tid, float (*t)[33]) {
    int c = tid & 31, r8 = tid >> 5;
#pragma unroll
    for (int i = 0; i < 4; i++) {
        int r = r8 + i * 8;
        t[r][c] = W[(size_t)(k0 + r) * N + n0 + c];
    }
    __syncthreads();
#pragma unroll
    for (int i = 0; i < 4; i++) {
        int r = r8 + i * 8;
        Wt[(size_t)(n0 + r) * K + k0 + c] = f2bf(t[c][r]);
    }
}

__global__ __launch_bounds__(256) void prep_kernel(
        const float* __restrict__ x, unsigned short* __restrict__ xb,
        const float* __restrict__ W1, unsigned short* __restrict__ W1t,
        const float* __restrict__ W2, unsigned short* __restrict__ W2t) {
    __shared__ float t[32][33];
    int b = blockIdx.x, tid = threadIdx.x;
    if (b < 4096) {
        int i = b * 256 + tid;
        float4 a = ((const float4*)x)[i];
        ushort4 o;
        o.x = f2bf(a.x); o.y = f2bf(a.y); o.z = f2bf(a.z); o.w = f2bf(a.w);
        ((ushort4*)xb)[i] = o;
    } else if (b < 6144) {
        int bb = b - 4096;                       // W1: K=512, N=4096
        transpose_body(W1, W1t, F_IN, HID1, (bb >> 7) * 32, (bb & 127) * 32, tid, t);
    } else {
        int bb = b - 6144;                       // W2: K=4096, N=1024
        transpose_body(W2, W2t, HID1, HID2, (bb >> 5) * 32, (bb & 31) * 32, tid, t);
    }
}

// ---------------------------------------------------------------------------
// agg1: agg_x[v,:] = sum_e w_e*xb[src,:] + xb[v,:]/(deg+1) -> bf16
// F=512 bf16: 128 lanes/node x ushort4; 2 nodes per block. Edge loop x2.
// ---------------------------------------------------------------------------
__global__ __launch_bounds__(256) void agg1_kernel(
        const unsigned short* __restrict__ xb, const int* __restrict__ row_ptr,
        const int* __restrict__ csr_src, const float* __restrict__ csr_w,
        const int* __restrict__ deg, unsigned short* __restrict__ out) {
    int v = blockIdx.x * 2 + (threadIdx.x >> 7);
    int t = threadIdx.x & 127;
    const ushort4* x4 = (const ushort4*)xb;    // row stride 128
    float sw = 1.0f / (float)(deg[v] + 1);
    ushort4 a = x4[(size_t)v * 128 + t];
    float ax = sw * bf2f(a.x), ay = sw * bf2f(a.y), az = sw * bf2f(a.z), aw = sw * bf2f(a.w);
    int e = row_ptr[v], end = row_ptr[v + 1];
    for (; e + 2 <= end; e += 2) {
        int s0 = csr_src[e], s1 = csr_src[e + 1];
        float w0 = csr_w[e], w1 = csr_w[e + 1];
        ushort4 b0 = x4[(size_t)s0 * 128 + t];
        ushort4 b1 = x4[(size_t)s1 * 128 + t];
        ax += w0 * bf2f(b0.x) + w1 * bf2f(b1.x);
        ay += w0 * bf2f(b0.y) + w1 * bf2f(b1.y);
        az += w0 * bf2f(b0.z) + w1 * bf2f(b1.z);
        aw += w0 * bf2f(b0.w) + w1 * bf2f(b1.w);
    }
    if (e < end) {
        int s = csr_src[e];
        float w = csr_w[e];
        ushort4 b = x4[(size_t)s * 128 + t];
        ax += w * bf2f(b.x); ay += w * bf2f(b.y); az += w * bf2f(b.z); aw += w * bf2f(b.w);
    }
    ushort4 o;
    o.x = f2bf(ax); o.y = f2bf(ay); o.z = f2bf(az); o.w = f2bf(aw);
    ((ushort4*)out)[(size_t)v * 128 + t] = o;
}

// ---------------------------------------------------------------------------
// agg2: relu(sum_e w_e*h[src,:] + h[v,:]/(deg+1) + b2) -> bf16
// F=1024 bf16: 256 lanes x ushort4; 1 node per block. Edge loop x2.
// ---------------------------------------------------------------------------
__global__ __launch_bounds__(256) void agg2_kernel(
        const unsigned short* __restrict__ h, const int* __restrict__ row_ptr,
        const int* __restrict__ csr_src, const float* __restrict__ csr_w,
        const int* __restrict__ deg, const float* __restrict__ bias,
        unsigned short* __restrict__ out) {
    int v = blockIdx.x;
    int t = threadIdx.x;
    const ushort4* h4 = (const ushort4*)h;     // row stride 256
    float sw = 1.0f / (float)(deg[v] + 1);
    ushort4 a = h4[(size_t)v * 256 + t];
    float ax = sw * bf2f(a.x), ay = sw * bf2f(a.y), az = sw * bf2f(a.z), aw = sw * bf2f(a.w);
    int e = row_ptr[v], end = row_ptr[v + 1];
    for (; e + 2 <= end; e += 2) {
        int s0 = csr_src[e], s1 = csr_src[e + 1];
        float w0 = csr_w[e], w1 = csr_w[e + 1];
        ushort4 b0 = h4[(size_t)s0 * 256 + t];
        ushort4 b1 = h4[(size_t)s1 * 256 + t];
        ax += w0 * bf2f(b0.x) + w1 * bf2f(b1.x);
        ay += w0 * bf2f(b0.y) + w1 * bf2f(b1.y);
        az += w0 * bf2f(b0.z) + w1 * bf2f(b1.z);
        aw += w0 * bf2f(b0.w) + w1 * bf2f(b1.w);
    }
    if (e < end) {
        int s = csr_src[e];
        float w = csr_w[e];
        ushort4 b = h4[(size_t)s * 256 + t];
        ax += w * bf2f(b.x); ay += w * bf2f(b.y); az += w * bf2f(b.z); aw += w * bf2f(b.w);
    }
    float4 bb = ((const float4*)bias)[t];
    ushort4 o;
    o.x = f2bf(fmaxf(ax + bb.x, 0.0f)); o.y = f2bf(fmaxf(ay + bb.y, 0.0f));
    o.z = f2bf(fmaxf(az + bb.z, 0.0f)); o.w = f2bf(fmaxf(aw + bb.w, 0.0f));
    ((ushort4*)out)[(size_t)v * 256 + t] = o;
}

// ---------------------------------------------------------------------------
// MFMA bf16 GEMM: C[M,N] = A[M,K] @ Bt[N,K]^T (+bias,relu)
// 128x128 tile, BK=64, XOR-swizzled LDS (conflict-free), XCD-aware swizzle.
// ---------------------------------------------------------------------------
template <bool OUT_BF16, bool BIAS, bool RELU>
__global__ __launch_bounds__(256) void gemm_mfma_kernel(
        const unsigned short* __restrict__ A,   // [M,K] bf16
        const unsigned short* __restrict__ Bt,  // [N,K] bf16
        const float* __restrict__ bias,         // [N] or null
        void* __restrict__ C,                   // [M,N] bf16 or f32
        int M, int N, int K) {
    __shared__ unsigned short As[128 * 64];
    __shared__ unsigned short Bs[128 * 64];
    int tid = threadIdx.x;
    int wave = tid >> 6, lane = tid & 63;
    int wm = wave >> 1, wn = wave & 1;
    int GN = N >> 7;
    int b = blockIdx.x;
    int ntile = (b >> 3) % GN;
    int mtile = ((b >> 3) / GN) * 8 + (b & 7);
    int m0 = mtile * 128, n0 = ntile * 128;
    int lrow = lane & 15, lquad = lane >> 4;

    floatx4 acc[4][4] = {};

    for (int k0 = 0; k0 < K; k0 += 64) {
#pragma unroll
        for (int j = 0; j < 4; j++) {
            int idx = j * 256 + tid;            // LDS 16B-slot 0..1023
            int r = idx >> 3;                   // row 0..127
            int kc = (idx & 7) ^ (r & 7);       // XOR swizzle on source chunk
            __builtin_amdgcn_global_load_lds(
                (const __attribute__((address_space(1))) void*)(A + (size_t)(m0 + r) * K + k0 + kc * 8),
                (__attribute__((address_space(3))) void*)(&As[idx * 8]), 16, 0, 0);
            __builtin_amdgcn_global_load_lds(
                (const __attribute__((address_space(1))) void*)(Bt + (size_t)(n0 + r) * K + k0 + kc * 8),
                (__attribute__((address_space(3))) void*)(&Bs[idx * 8]), 16, 0, 0);
        }
        __syncthreads();
#pragma unroll
        for (int kk = 0; kk < 2; kk++) {
            bf16x8 af[4], bfr[4];
#pragma unroll
            for (int mt = 0; mt < 4; mt++) {
                int R = wm * 64 + mt * 16 + lrow;
                int c = kk * 4 + lquad;
                af[mt] = *(const bf16x8*)&As[(R * 8 + (c ^ (R & 7))) * 8];
            }
#pragma unroll
            for (int nt = 0; nt < 4; nt++) {
                int R = wn * 64 + nt * 16 + lrow;
                int c = kk * 4 + lquad;
                bfr[nt] = *(const bf16x8*)&Bs[(R * 8 + (c ^ (R & 7))) * 8];
            }
#pragma unroll
            for (int mt = 0; mt < 4; mt++)
#pragma unroll
                for (int nt = 0; nt < 4; nt++)
                    acc[mt][nt] = __builtin_amdgcn_mfma_f32_16x16x32_bf16(
                        af[mt], bfr[nt], acc[mt][nt], 0, 0, 0);
        }
        __syncthreads();
    }

#pragma unroll
    for (int mt = 0; mt < 4; mt++) {
#pragma unroll
        for (int nt = 0; nt < 4; nt++) {
            int col = n0 + wn * 64 + nt * 16 + lrow;
            float bv = BIAS ? bias[col] : 0.0f;
#pragma unroll
            for (int r = 0; r < 4; r++) {
                int row = m0 + wm * 64 + mt * 16 + lquad * 4 + r;
                float v = acc[mt][nt][r] + bv;
                if (RELU) v = fmaxf(v, 0.0f);
                if (OUT_BF16)
                    ((unsigned short*)C)[(size_t)row * N + col] = f2bf(v);
                else
                    ((float*)C)[(size_t)row * N + col] = v;
            }
        }
    }
}

// ---------------------------------------------------------------------------
// GEMM3: H3[8192,10(s12)] = agg2b[8192,1024](bf16) @ W3[1024,10](f32)
// 32 rows/block, W3 in LDS, 8 lanes per row (interleaved k), shfl reduce.
// ---------------------------------------------------------------------------
__global__ __launch_bounds__(256) void gemm3_kernel(const unsigned short* __restrict__ A,
                                                    const float* __restrict__ W3,
                                                    float* __restrict__ H3) {
    __shared__ float w3s[HID2 * F_OUT];        // 40 KB
    int tid = threadIdx.x;
    for (int i = tid; i < HID2 * F_OUT; i += 256) w3s[i] = W3[i];
    __syncthreads();
    int r = tid >> 3, sub = tid & 7;
    int row = blockIdx.x * 32 + r;
    const ushort4* a4p = (const ushort4*)A + (size_t)row * 256;
    float acc[F_OUT] = {};
#pragma unroll
    for (int i = 0; i < 32; i++) {
        ushort4 a = a4p[i * 8 + sub];          // k = i*32 + sub*4
        int k = i * 32 + sub * 4;
        float a0 = bf2f(a.x), a1 = bf2f(a.y), a2 = bf2f(a.z), a3 = bf2f(a.w);
#pragma unroll
        for (int c = 0; c < F_OUT; c++)
            acc[c] += a0 * w3s[k * F_OUT + c] + a1 * w3s[(k + 1) * F_OUT + c] +
                      a2 * w3s[(k + 2) * F_OUT + c] + a3 * w3s[(k + 3) * F_OUT + c];
    }
#pragma unroll
    for (int c = 0; c < F_OUT; c++) {
        acc[c] += __shfl_xor(acc[c], 1, 64);
        acc[c] += __shfl_xor(acc[c], 2, 64);
        acc[c] += __shfl_xor(acc[c], 4, 64);
    }
    if (sub == 0) {
#pragma unroll
        for (int c = 0; c < F_OUT; c++) H3[row * H3_STRIDE + c] = acc[c];
    }
}

// ---------------------------------------------------------------------------
// Final: aggregate h3 (stride 12), add b3, log_softmax per node.
// ---------------------------------------------------------------------------
__global__ void final_kernel(const float* __restrict__ h3, const int* __restrict__ row_ptr,
                             const int* __restrict__ csr_src, const float* __restrict__ csr_w,
                             const int* __restrict__ deg, const float* __restrict__ b3,
                             float* __restrict__ out) {
    int v = blockIdx.x * blockDim.x + threadIdx.x;
    if (v >= N_NODES) return;
    const float4* h4 = (const float4*)h3;      // row = 3 float4
    float sw = 1.0f / (float)(deg[v] + 1);
    float a[12];
    *(float4*)&a[0] = h4[v * 3];
    *(float4*)&a[4] = h4[v * 3 + 1];
    *(float4*)&a[8] = h4[v * 3 + 2];
    float acc[F_OUT];
#pragma unroll
    for (int c = 0; c < F_OUT; c++) acc[c] = b3[c] + sw * a[c];
    int end = row_ptr[v + 1];
    for (int e = row_ptr[v]; e < end; e++) {
        int s = csr_src[e];
        float w = csr_w[e];
        float bsrc[12];
        *(float4*)&bsrc[0] = h4[s * 3];
        *(float4*)&bsrc[4] = h4[s * 3 + 1];
        *(float4*)&bsrc[8] = h4[s * 3 + 2];
#pragma unroll
        for (int c = 0; c < F_OUT; c++) acc[c] += w * bsrc[c];
    }
    float m = acc[0];
#pragma unroll
    for (int c = 1; c < F_OUT; c++) m = fmaxf(m, acc[c]);
    float ssum = 0.0f;
#pragma unroll
    for (int c = 0; c < F_OUT; c++) ssum += expf(acc[c] - m);
    float l = logf(ssum);
#pragma unroll
    for (int c = 0; c < F_OUT; c++) out[v * F_OUT + c] = acc[c] - m - l;
}

// ---------------------------------------------------------------------------
// Launch
// ---------------------------------------------------------------------------
extern "C" void kernel_launch(void* const* d_in, const int* in_sizes, int n_in,
                              void* d_out, int out_size, void* d_ws, size_t ws_size,
                              hipStream_t stream) {
    const float* x  = (const float*)d_in[0];
    const float* W1 = (const float*)d_in[1];
    const float* b1 = (const float*)d_in[2];
    const float* W2 = (const float*)d_in[3];
    const float* b2 = (const float*)d_in[4];
    const float* W3 = (const float*)d_in[5];
    const float* b3 = (const float*)d_in[6];
    const int*   ei = (const int*)d_in[7];
    float* out = (float*)d_out;

    char* p = (char*)d_ws;
    int*   deg     = (int*)p;    p += N_NODES * 4;
    int*   cnt     = (int*)p;    p += N_NODES * 4;
    int*   row_ptr = (int*)p;    p += 33024;
    int*   csr_src = (int*)p;    p += N_EDGES * 4;
    float* csr_w   = (float*)p;  p += N_EDGES * 4;
    float* h3      = (float*)p;  p += N_NODES * H3_STRIDE * 4;
    unsigned short* xb    = (unsigned short*)p; p += (size_t)N_NODES * F_IN * 2;
    unsigned short* agg_x = (unsigned short*)p; p += (size_t)N_NODES * F_IN * 2;
    unsigned short* W1t   = (unsigned short*)p; p += (size_t)HID1 * F_IN * 2;
    unsigned short* W2t   = (unsigned short*)p; p += (size_t)HID2 * HID1 * 2;
    unsigned short* h1    = (unsigned short*)p; p += (size_t)N_NODES * HID1 * 2;
    unsigned short* h2pre = (unsigned short*)p; p += (size_t)N_NODES * HID2 * 2;
    unsigned short* agg2b = (unsigned short*)p; p += (size_t)N_NODES * HID2 * 2;

    // Graph preprocessing
    hipMemsetAsync(deg, 0, N_NODES * 4, stream);
    deg_kernel<<<N_EDGES / 256, 256, 0, stream>>>(ei, deg);
    scan_kernel<<<1, 1024, 0, stream>>>(deg, row_ptr, cnt);
    fill_kernel<<<N_EDGES / 256, 256, 0, stream>>>(ei, deg, row_ptr, cnt, csr_src, csr_w);

    // Conversions (xcvt + W1/W2 transpose in one launch)
    prep_kernel<<<10240, 256, 0, stream>>>(x, xb, W1, W1t, W2, W2t);

    // Layer 1
    agg1_kernel<<<N_NODES / 2, 256, 0, stream>>>(xb, row_ptr, csr_src, csr_w, deg, agg_x);
    gemm_mfma_kernel<true, true, true><<<(HID1 / 128) * (N_NODES / 128), 256, 0, stream>>>(
        agg_x, W1t, b1, h1, N_NODES, HID1, F_IN);

    // Layer 2
    gemm_mfma_kernel<true, false, false><<<(HID2 / 128) * (N_NODES / 128), 256, 0, stream>>>(
        h1, W2t, nullptr, h2pre, N_NODES, HID2, HID1);
    agg2_kernel<<<N_NODES, 256, 0, stream>>>(h2pre, row_ptr, csr_src, csr_w, deg, b2, agg2b);

    // Layer 3
    gemm3_kernel<<<N_NODES / 32, 256, 0, stream>>>(agg2b, W3, h3);
    final_kernel<<<N_NODES / 256, 256, 0, stream>>>(h3, row_ptr, csr_src, csr_w, deg, b3, out);
}